// Round 3
// baseline (405.626 us; speedup 1.0000x reference)
//
#include <hip/hip_runtime.h>

// GCN layer on MI355X (gfx950) — ALL tensors fp32.
// x[100000,512], edge_index[2,3200000] i32, W1[512,16], b1[16], W2[16,2], b2[2]
//   -> out[100000,2] fp32.
//
// Folds (epilogue is linear):
//   Wc = W1@W2 [512,2],  b' = b1@W2 + b2
//   t_raw[j] = (x@Wc)[j];  after deg known: t[j] = dinv[j]*t_raw[j]
//   out_i = dinv_i * ( sum_{j->i} t_j + t_i ) + b'
//
// R8 changes (balance + write-locality + MLP):
//  - Buckets 256 -> 64 nodes (NBUCK 391 -> 1563). k_dinv/k_acc: 1563 blocks
//    x 256 thr => ~6 blocks/CU dynamic balance (was 1.31x makespan tail).
//  - Binning blocks 320 -> 128 (EPB 25000): per-(block,bucket) run length
//    = 25000/1563 ~ 16 edges = 64 B = one cache line => fewer cross-XCD
//    partial-line RMWs on binned (R0 showed 4.6x write amplification).
//  - xw: 4 nodes/wave (8 independent dwordx4 in flight = 128 B/lane).
//  - basescan: 1563-entry scan via 2 elems/thread in one 1024-thr block.

constexpr int N_NODES = 100000;
constexpr int N_EDGES = 3200000;
constexpr int IN_CH   = 512;
constexpr int HID     = 16;
constexpr int OUT_CH  = 2;

constexpr int BSHIFT = 6;                              // 64-node buckets
constexpr int BSIZE  = 1 << BSHIFT;
constexpr int NBUCK  = (N_NODES + BSIZE - 1) / BSIZE;  // 1563
constexpr int BIN_BLOCKS = 128;
constexpr int EPB        = N_EDGES / BIN_BLOCKS;       // 25000 (exact)
constexpr int XW_BLOCKS  = (N_NODES + 63) / 64;        // 1563 (64 nodes/block)

typedef __attribute__((ext_vector_type(4))) float floatx4;

// ---- workspace layout (bytes) ----
// 0        hist     int[128][1563] (800256)  per-block bucket counts -> offsets
// 800256   coltot   int[1563]      (6252)
// 806512   bbase    int[1564]      (6256)
// 812768   Wc       float[1024]    (4096)
// 816864   bconst   float[2] (pad 16)
// 816880   dinv     float[N_NODES]   (400000)
// 1216880  t2       float2[N_NODES]  (800000)
// 2016896  binned   int[N_EDGES]     (12.8 MB)  value = (local_tgt<<20)|src

__global__ __launch_bounds__(1024) void k_count_wc(const int* __restrict__ tgt,
                                                   int* __restrict__ hist,
                                                   const float* __restrict__ W1,
                                                   const float* __restrict__ b1,
                                                   const float* __restrict__ W2,
                                                   const float* __restrict__ b2,
                                                   float* __restrict__ Wc,
                                                   float* __restrict__ bconst) {
    if (blockIdx.x == BIN_BLOCKS) {  // weight-fold block
        for (int i = threadIdx.x; i < IN_CH * OUT_CH; i += 1024) {
            int c = i >> 1, o = i & 1;
            float s = 0.f;
#pragma unroll
            for (int h = 0; h < HID; ++h) s += W1[c * HID + h] * W2[h * OUT_CH + o];
            Wc[i] = s;
        }
        if (threadIdx.x < OUT_CH) {
            float bo = b2[threadIdx.x];
#pragma unroll
            for (int h = 0; h < HID; ++h) bo += b1[h] * W2[h * OUT_CH + threadIdx.x];
            bconst[threadIdx.x] = bo;
        }
        return;
    }
    __shared__ int h[NBUCK];
    for (int i = threadIdx.x; i < NBUCK; i += 1024) h[i] = 0;
    __syncthreads();
    int e0 = blockIdx.x * EPB;
    for (int e = e0 + threadIdx.x; e < e0 + EPB; e += 1024)
        atomicAdd(&h[tgt[e] >> BSHIFT], 1);
    __syncthreads();
    for (int i = threadIdx.x; i < NBUCK; i += 1024)
        hist[blockIdx.x * NBUCK + i] = h[i];  // dense row, single-writer line
}

// Per bucket b: exclusive scan down the 128-block column; in-place offsets.
__global__ __launch_bounds__(64) void k_colscan(int* __restrict__ hist,
                                                int* __restrict__ coltot) {
    int b = blockIdx.x;
    int lane = threadIdx.x;          // covers blocks 2*lane .. 2*lane+1
    int v[2];
    int s = 0;
#pragma unroll
    for (int j = 0; j < 2; ++j) {
        v[j] = hist[(lane * 2 + j) * NBUCK + b];
        s += v[j];
    }
    int inc = s;
#pragma unroll
    for (int off = 1; off < 64; off <<= 1) {
        int n = __shfl_up(inc, off);
        if (lane >= off) inc += n;
    }
    int excl = inc - s;
#pragma unroll
    for (int j = 0; j < 2; ++j) {
        hist[(lane * 2 + j) * NBUCK + b] = excl;
        excl += v[j];
    }
    if (lane == 63) coltot[b] = inc;
}

// Exclusive scan of coltot[1563] -> bbase[0..1563], bbase[NBUCK] = N_EDGES.
// 1024 threads, 2 elements each.
__global__ __launch_bounds__(1024) void k_basescan(const int* __restrict__ coltot,
                                                   int* __restrict__ bbase) {
    __shared__ int psum[1024];
    int tid = threadIdx.x;
    int i0 = 2 * tid, i1 = 2 * tid + 1;
    int v0 = (i0 < NBUCK) ? coltot[i0] : 0;
    int v1 = (i1 < NBUCK) ? coltot[i1] : 0;
    psum[tid] = v0 + v1;
    __syncthreads();
#pragma unroll
    for (int off = 1; off < 1024; off <<= 1) {
        int tv = (tid >= off) ? psum[tid - off] : 0;
        __syncthreads();
        psum[tid] += tv;
        __syncthreads();
    }
    int excl = psum[tid] - (v0 + v1);         // inclusive - own = exclusive
    if (i0 < NBUCK) bbase[i0] = excl;
    if (i1 < NBUCK) bbase[i1] = excl + v0;
    if (tid == 1023) bbase[NBUCK] = psum[1023];  // = N_EDGES
}

// Blocks [0,128): single-pass bin placement with precomputed cursors.
// Blocks [128,1691): t_raw = x@Wc, 4 nodes/wave, 64 nodes/1024-thr block.
__global__ __launch_bounds__(1024) void k_bin_xw(const int* __restrict__ ei,
                                                 int* __restrict__ hist,
                                                 const int* __restrict__ bbase,
                                                 int* __restrict__ binned,
                                                 const float* __restrict__ x,
                                                 const float* __restrict__ Wc,
                                                 float2* __restrict__ t2) {
    if (blockIdx.x < BIN_BLOCKS) {
        __shared__ int lcur[NBUCK];
        int blk = blockIdx.x;
        for (int i = threadIdx.x; i < NBUCK; i += 1024)
            lcur[i] = bbase[i] + hist[blk * NBUCK + i];
        __syncthreads();
        int e0 = blk * EPB;
        for (int e = e0 + threadIdx.x; e < e0 + EPB; e += 1024) {
            int tg = ei[N_EDGES + e];
            int b = tg >> BSHIFT;
            int pos = atomicAdd(&lcur[b], 1);
            binned[pos] = ((tg & (BSIZE - 1)) << 20) | ei[e];  // src < 2^20
        }
        return;
    }
    int nb = blockIdx.x - BIN_BLOCKS;
    int wv = threadIdx.x >> 6;
    int lane = threadIdx.x & 63;
    int node = nb * 64 + wv * 4;                 // this wave's 4 nodes
    int r0 = min(node,     N_NODES - 1);
    int r1 = min(node + 1, N_NODES - 1);
    int r2 = min(node + 2, N_NODES - 1);
    int r3 = min(node + 3, N_NODES - 1);
    const floatx4* x0 = reinterpret_cast<const floatx4*>(x + (size_t)r0 * IN_CH + lane * 8);
    const floatx4* x1 = reinterpret_cast<const floatx4*>(x + (size_t)r1 * IN_CH + lane * 8);
    const floatx4* x2 = reinterpret_cast<const floatx4*>(x + (size_t)r2 * IN_CH + lane * 8);
    const floatx4* x3 = reinterpret_cast<const floatx4*>(x + (size_t)r3 * IN_CH + lane * 8);
    const floatx4* wr = reinterpret_cast<const floatx4*>(Wc + lane * 16);
    floatx4 a0 = x0[0], a1 = x0[1];              // 8 x-loads issued back-to-back
    floatx4 b0 = x1[0], b1 = x1[1];
    floatx4 c0 = x2[0], c1 = x2[1];
    floatx4 d0 = x3[0], d1 = x3[1];
    floatx4 w0 = wr[0], w1 = wr[1], w2 = wr[2], w3 = wr[3];
    float s0x = a0[0]*w0[0] + a0[1]*w0[2] + a0[2]*w1[0] + a0[3]*w1[2]
              + a1[0]*w2[0] + a1[1]*w2[2] + a1[2]*w3[0] + a1[3]*w3[2];
    float s0y = a0[0]*w0[1] + a0[1]*w0[3] + a0[2]*w1[1] + a0[3]*w1[3]
              + a1[0]*w2[1] + a1[1]*w2[3] + a1[2]*w3[1] + a1[3]*w3[3];
    float s1x = b0[0]*w0[0] + b0[1]*w0[2] + b0[2]*w1[0] + b0[3]*w1[2]
              + b1[0]*w2[0] + b1[1]*w2[2] + b1[2]*w3[0] + b1[3]*w3[2];
    float s1y = b0[0]*w0[1] + b0[1]*w0[3] + b0[2]*w1[1] + b0[3]*w1[3]
              + b1[0]*w2[1] + b1[1]*w2[3] + b1[2]*w3[1] + b1[3]*w3[3];
    float s2x = c0[0]*w0[0] + c0[1]*w0[2] + c0[2]*w1[0] + c0[3]*w1[2]
              + c1[0]*w2[0] + c1[1]*w2[2] + c1[2]*w3[0] + c1[3]*w3[2];
    float s2y = c0[0]*w0[1] + c0[1]*w0[3] + c0[2]*w1[1] + c0[3]*w1[3]
              + c1[0]*w2[1] + c1[1]*w2[3] + c1[2]*w3[1] + c1[3]*w3[3];
    float s3x = d0[0]*w0[0] + d0[1]*w0[2] + d0[2]*w1[0] + d0[3]*w1[2]
              + d1[0]*w2[0] + d1[1]*w2[2] + d1[2]*w3[0] + d1[3]*w3[2];
    float s3y = d0[0]*w0[1] + d0[1]*w0[3] + d0[2]*w1[1] + d0[3]*w1[3]
              + d1[0]*w2[1] + d1[1]*w2[3] + d1[2]*w3[1] + d1[3]*w3[3];
#pragma unroll
    for (int off = 32; off; off >>= 1) {         // 8 chains interleaved (ILP)
        s0x += __shfl_xor(s0x, off); s0y += __shfl_xor(s0y, off);
        s1x += __shfl_xor(s1x, off); s1y += __shfl_xor(s1y, off);
        s2x += __shfl_xor(s2x, off); s2y += __shfl_xor(s2y, off);
        s3x += __shfl_xor(s3x, off); s3y += __shfl_xor(s3y, off);
    }
    if (node + lane < N_NODES) {                 // static accumulator select
        if      (lane == 0) t2[node]     = make_float2(s0x, s0y);
        else if (lane == 1) t2[node + 1] = make_float2(s1x, s1y);
        else if (lane == 2) t2[node + 2] = make_float2(s2x, s2y);
        else if (lane == 3) t2[node + 3] = make_float2(s3x, s3y);
    }
}

// Per bucket: local degree count -> dinv; scale t2 in place.
__global__ __launch_bounds__(256) void k_dinv(const int* __restrict__ bbase,
                                              const int* __restrict__ binned,
                                              float* __restrict__ dinv,
                                              float2* __restrict__ t2) {
    __shared__ int cnt[BSIZE];
    if (threadIdx.x < BSIZE) cnt[threadIdx.x] = 0;
    __syncthreads();
    int b = blockIdx.x;
    int s = bbase[b], e = bbase[b + 1];
    for (int i = s + threadIdx.x; i < e; i += 256)
        atomicAdd(&cnt[binned[i] >> 20], 1);
    __syncthreads();
    if (threadIdx.x < BSIZE) {
        int node = (b << BSHIFT) + threadIdx.x;
        if (node < N_NODES) {
            float di = rsqrtf((float)(cnt[threadIdx.x] + 1));  // +1 self loop
            dinv[node] = di;
            float2 v = t2[node];
            t2[node] = make_float2(v.x * di, v.y * di);
        }
    }
}

// Per bucket: accumulate pre-scaled t[src] in LDS, fused epilogue, dense out.
__global__ __launch_bounds__(256) void k_acc(const int* __restrict__ bbase,
                                             const int* __restrict__ binned,
                                             const float2* __restrict__ t2,
                                             const float* __restrict__ dinv,
                                             const float* __restrict__ bconst,
                                             float2* __restrict__ out) {
    __shared__ float acc0[BSIZE];
    __shared__ float acc1[BSIZE];
    if (threadIdx.x < BSIZE) {
        acc0[threadIdx.x] = 0.f;
        acc1[threadIdx.x] = 0.f;
    }
    __syncthreads();
    int b = blockIdx.x;
    int s = bbase[b], e = bbase[b + 1];
    for (int i = s + threadIdx.x; i < e; i += 256) {
        int v = binned[i];
        float2 ts = t2[v & 0xFFFFF];    // L2-resident 800 KB table
        atomicAdd(&acc0[v >> 20], ts.x);
        atomicAdd(&acc1[v >> 20], ts.y);
    }
    __syncthreads();
    if (threadIdx.x < BSIZE) {
        int node = (b << BSHIFT) + threadIdx.x;
        if (node < N_NODES) {
            float2 self = t2[node];     // already dinv-scaled
            float di = dinv[node];
            out[node] = make_float2(di * (acc0[threadIdx.x] + self.x) + bconst[0],
                                    di * (acc1[threadIdx.x] + self.y) + bconst[1]);
        }
    }
}

extern "C" void kernel_launch(void* const* d_in, const int* in_sizes, int n_in,
                              void* d_out, int out_size, void* d_ws, size_t ws_size,
                              hipStream_t stream) {
    const float* x  = (const float*)d_in[0];
    const int*   ei = (const int*)d_in[1];
    const float* W1 = (const float*)d_in[2];
    const float* b1 = (const float*)d_in[3];
    const float* W2 = (const float*)d_in[4];
    const float* b2 = (const float*)d_in[5];

    char* ws = (char*)d_ws;
    int*    hist   = (int*)   (ws + 0);
    int*    coltot = (int*)   (ws + 800256);
    int*    bbase  = (int*)   (ws + 806512);
    float*  Wc     = (float*) (ws + 812768);
    float*  bconst = (float*) (ws + 816864);
    float*  dinv   = (float*) (ws + 816880);
    float2* t2     = (float2*)(ws + 1216880);
    int*    binned = (int*)   (ws + 2016896);

    k_count_wc<<<BIN_BLOCKS + 1, 1024, 0, stream>>>(ei + N_EDGES, hist,
                                                    W1, b1, W2, b2, Wc, bconst);
    k_colscan <<<NBUCK, 64, 0, stream>>>(hist, coltot);
    k_basescan<<<1, 1024, 0, stream>>>(coltot, bbase);
    k_bin_xw  <<<BIN_BLOCKS + XW_BLOCKS, 1024, 0, stream>>>(ei, hist, bbase,
                                                            binned, x, Wc, t2);
    k_dinv    <<<NBUCK, 256, 0, stream>>>(bbase, binned, dinv, t2);
    k_acc     <<<NBUCK, 256, 0, stream>>>(bbase, binned, t2, dinv, bconst,
                                          (float2*)d_out);
}

// Round 4
// 371.424 us; speedup vs baseline: 1.0921x; 1.0921x over previous
//
#include <hip/hip_runtime.h>

// GCN layer on MI355X (gfx950) — ALL tensors fp32.
// x[100000,512], edge_index[2,3200000] i32, W1[512,16], b1[16], W2[16,2], b2[2]
//   -> out[100000,2] fp32.
//
// Folds (epilogue is linear):
//   Wc = W1@W2 [512,2],  b' = b1@W2 + b2
//   t_raw[j] = (x@Wc)[j];  after deg known: t[j] = dinv[j]*t_raw[j]
//   out_i = dinv_i * ( sum_{j->i} t_j + t_i ) + b'
//
// R9: revert to R7 bucket geometry (256-node buckets, NBUCK=391,
// BIN_BLOCKS=320, 1024-thr dinv/acc) + LDS write-combining in the binning
// phase. Evidence: k_bin_xw duration was invariant (~122-126us) across 3
// thread/bucket geometries with WRITE_SIZE 73MB for 13.6MB logical writes
// (5.4x partial-line RMW amplification from 3.2M scattered 4B stores).
// Fix: stage each block's 10000 edges bucket-ordered in LDS (40KB), then
// copy out run-per-wave as coalesced full-line bursts.

constexpr int N_NODES = 100000;
constexpr int N_EDGES = 3200000;
constexpr int IN_CH   = 512;
constexpr int HID     = 16;
constexpr int OUT_CH  = 2;

constexpr int NBUCK      = (N_NODES + 255) / 256;   // 391 buckets x 256 nodes
constexpr int BIN_BLOCKS = 320;
constexpr int EPB        = N_EDGES / BIN_BLOCKS;    // 10000 (exact)
constexpr int XW_BLOCKS  = (N_NODES + 63) / 64;     // 1563 (64 nodes/block)

typedef __attribute__((ext_vector_type(4))) float floatx4;

// ---- workspace layout (bytes) ----
// 0        hist     int[320][391]  (500480)  per-block bucket counts -> offsets
// 500480   coltot   int[391]
// 502048   bbase    int[392]
// 503616   Wc       float[1024]
// 507712   bconst   float[2] (pad 16)
// 507728   dinv     float[N_NODES]   (400000)
// 907728   t2       float2[N_NODES]  (800000)
// 1707728  binned   int[N_EDGES]     (12.8 MB)  value = (local_tgt<<20)|src

__global__ __launch_bounds__(1024) void k_count_wc(const int* __restrict__ tgt,
                                                   int* __restrict__ hist,
                                                   const float* __restrict__ W1,
                                                   const float* __restrict__ b1,
                                                   const float* __restrict__ W2,
                                                   const float* __restrict__ b2,
                                                   float* __restrict__ Wc,
                                                   float* __restrict__ bconst) {
    if (blockIdx.x == BIN_BLOCKS) {  // weight-fold block
        for (int i = threadIdx.x; i < IN_CH * OUT_CH; i += 1024) {
            int c = i >> 1, o = i & 1;
            float s = 0.f;
#pragma unroll
            for (int h = 0; h < HID; ++h) s += W1[c * HID + h] * W2[h * OUT_CH + o];
            Wc[i] = s;
        }
        if (threadIdx.x < OUT_CH) {
            float bo = b2[threadIdx.x];
#pragma unroll
            for (int h = 0; h < HID; ++h) bo += b1[h] * W2[h * OUT_CH + threadIdx.x];
            bconst[threadIdx.x] = bo;
        }
        return;
    }
    __shared__ int h[NBUCK];
    for (int i = threadIdx.x; i < NBUCK; i += 1024) h[i] = 0;
    __syncthreads();
    int e0 = blockIdx.x * EPB;
    for (int e = e0 + threadIdx.x; e < e0 + EPB; e += 1024)
        atomicAdd(&h[tgt[e] >> 8], 1);
    __syncthreads();
    for (int i = threadIdx.x; i < NBUCK; i += 1024)
        hist[blockIdx.x * NBUCK + i] = h[i];  // dense row, single-writer line
}

// Per bucket b: exclusive scan down the 320-block column; in-place offsets.
__global__ __launch_bounds__(64) void k_colscan(int* __restrict__ hist,
                                                int* __restrict__ coltot) {
    int b = blockIdx.x;
    int lane = threadIdx.x;          // covers blocks 5*lane .. 5*lane+4
    int v[5];
    int s = 0;
#pragma unroll
    for (int j = 0; j < 5; ++j) {
        v[j] = hist[(lane * 5 + j) * NBUCK + b];
        s += v[j];
    }
    int inc = s;
#pragma unroll
    for (int off = 1; off < 64; off <<= 1) {
        int n = __shfl_up(inc, off);
        if (lane >= off) inc += n;
    }
    int excl = inc - s;
#pragma unroll
    for (int j = 0; j < 5; ++j) {
        hist[(lane * 5 + j) * NBUCK + b] = excl;
        excl += v[j];
    }
    if (lane == 63) coltot[b] = inc;
}

__global__ __launch_bounds__(512) void k_basescan(const int* __restrict__ coltot,
                                                  int* __restrict__ bbase) {
    __shared__ int tmp[512];
    int tid = threadIdx.x;
    int v = (tid < NBUCK) ? coltot[tid] : 0;
    tmp[tid] = v;
    __syncthreads();
#pragma unroll
    for (int off = 1; off < 512; off <<= 1) {
        int tv = (tid >= off) ? tmp[tid - off] : 0;
        __syncthreads();
        tmp[tid] += tv;
        __syncthreads();
    }
    if (tid < NBUCK) bbase[tid] = tmp[tid] - v;
    if (tid == NBUCK - 1) bbase[NBUCK] = tmp[tid];  // = N_EDGES
}

// Blocks [0,320): binning with LDS write-combining — stage the block's
//   10000 edges bucket-ordered in LDS, then copy out run-per-wave as
//   coalesced bursts (full 64B lines instead of 3.2M scattered 4B RMWs).
// Blocks [320,1883): t_raw = x@Wc, 4 nodes/wave, 64 nodes/1024-thr block.
__global__ __launch_bounds__(1024) void k_bin_xw(const int* __restrict__ ei,
                                                 const int* __restrict__ hist,
                                                 const int* __restrict__ coltot,
                                                 const int* __restrict__ bbase,
                                                 int* __restrict__ binned,
                                                 const float* __restrict__ x,
                                                 const float* __restrict__ Wc,
                                                 float2* __restrict__ t2) {
    if (blockIdx.x < BIN_BLOCKS) {
        __shared__ int goff[NBUCK];   // this block's offset within bucket seg
        __shared__ int rlen[NBUCK];   // this block's run length per bucket
        __shared__ int lofs[512];     // scan array -> inclusive LDS offsets
        __shared__ int lcur[NBUCK];   // LDS staging cursors
        __shared__ int stage[EPB];    // 40 KB bucket-ordered staging
        int blk = blockIdx.x;
        int tid = threadIdx.x;
        for (int b = tid; b < NBUCK; b += 1024) {
            int g  = hist[blk * NBUCK + b];
            int nx = (blk == BIN_BLOCKS - 1) ? coltot[b]
                                             : hist[(blk + 1) * NBUCK + b];
            goff[b] = g;
            rlen[b] = nx - g;
        }
        __syncthreads();
        if (tid < 512) lofs[tid] = (tid < NBUCK) ? rlen[tid] : 0;
        __syncthreads();
#pragma unroll
        for (int off = 1; off < 512; off <<= 1) {   // inclusive Hillis-Steele
            int tv = 0;
            if (tid < 512 && tid >= off) tv = lofs[tid - off];
            __syncthreads();
            if (tid < 512) lofs[tid] += tv;
            __syncthreads();
        }
        for (int b = tid; b < NBUCK; b += 1024)
            lcur[b] = lofs[b] - rlen[b];            // exclusive LDS offset
        __syncthreads();
        int e0 = blk * EPB;
        for (int e = e0 + tid; e < e0 + EPB; e += 1024) {
            int tg = ei[N_EDGES + e];
            int b = tg >> 8;
            int lpos = atomicAdd(&lcur[b], 1);
            stage[lpos] = ((tg & 255) << 20) | ei[e];  // src < 2^20
        }
        __syncthreads();
        int wv = tid >> 6, lane = tid & 63;
        for (int b = wv; b < NBUCK; b += 16) {      // run-per-wave copy-out
            int len = rlen[b];
            int gbase = bbase[b] + goff[b];
            int lbase = lofs[b] - len;
            for (int i = lane; i < len; i += 64)
                binned[gbase + i] = stage[lbase + i];
        }
        return;
    }
    int nb = blockIdx.x - BIN_BLOCKS;
    int wv = threadIdx.x >> 6;
    int lane = threadIdx.x & 63;
    int node = nb * 64 + wv * 4;                 // this wave's 4 nodes
    int r0 = min(node,     N_NODES - 1);
    int r1 = min(node + 1, N_NODES - 1);
    int r2 = min(node + 2, N_NODES - 1);
    int r3 = min(node + 3, N_NODES - 1);
    const floatx4* x0 = reinterpret_cast<const floatx4*>(x + (size_t)r0 * IN_CH + lane * 8);
    const floatx4* x1 = reinterpret_cast<const floatx4*>(x + (size_t)r1 * IN_CH + lane * 8);
    const floatx4* x2 = reinterpret_cast<const floatx4*>(x + (size_t)r2 * IN_CH + lane * 8);
    const floatx4* x3 = reinterpret_cast<const floatx4*>(x + (size_t)r3 * IN_CH + lane * 8);
    const floatx4* wr = reinterpret_cast<const floatx4*>(Wc + lane * 16);
    floatx4 a0 = x0[0], a1 = x0[1];              // 8 x-loads issued back-to-back
    floatx4 b0 = x1[0], b1 = x1[1];
    floatx4 c0 = x2[0], c1 = x2[1];
    floatx4 d0 = x3[0], d1 = x3[1];
    floatx4 w0 = wr[0], w1 = wr[1], w2 = wr[2], w3 = wr[3];
    float s0x = a0[0]*w0[0] + a0[1]*w0[2] + a0[2]*w1[0] + a0[3]*w1[2]
              + a1[0]*w2[0] + a1[1]*w2[2] + a1[2]*w3[0] + a1[3]*w3[2];
    float s0y = a0[0]*w0[1] + a0[1]*w0[3] + a0[2]*w1[1] + a0[3]*w1[3]
              + a1[0]*w2[1] + a1[1]*w2[3] + a1[2]*w3[1] + a1[3]*w3[3];
    float s1x = b0[0]*w0[0] + b0[1]*w0[2] + b0[2]*w1[0] + b0[3]*w1[2]
              + b1[0]*w2[0] + b1[1]*w2[2] + b1[2]*w3[0] + b1[3]*w3[2];
    float s1y = b0[0]*w0[1] + b0[1]*w0[3] + b0[2]*w1[1] + b0[3]*w1[3]
              + b1[0]*w2[1] + b1[1]*w2[3] + b1[2]*w3[1] + b1[3]*w3[3];
    float s2x = c0[0]*w0[0] + c0[1]*w0[2] + c0[2]*w1[0] + c0[3]*w1[2]
              + c1[0]*w2[0] + c1[1]*w2[2] + c1[2]*w3[0] + c1[3]*w3[2];
    float s2y = c0[0]*w0[1] + c0[1]*w0[3] + c0[2]*w1[1] + c0[3]*w1[3]
              + c1[0]*w2[1] + c1[1]*w2[3] + c1[2]*w3[1] + c1[3]*w3[3];
    float s3x = d0[0]*w0[0] + d0[1]*w0[2] + d0[2]*w1[0] + d0[3]*w1[2]
              + d1[0]*w2[0] + d1[1]*w2[2] + d1[2]*w3[0] + d1[3]*w3[2];
    float s3y = d0[0]*w0[1] + d0[1]*w0[3] + d0[2]*w1[1] + d0[3]*w1[3]
              + d1[0]*w2[1] + d1[1]*w2[3] + d1[2]*w3[1] + d1[3]*w3[3];
#pragma unroll
    for (int off = 32; off; off >>= 1) {         // 8 chains interleaved (ILP)
        s0x += __shfl_xor(s0x, off); s0y += __shfl_xor(s0y, off);
        s1x += __shfl_xor(s1x, off); s1y += __shfl_xor(s1y, off);
        s2x += __shfl_xor(s2x, off); s2y += __shfl_xor(s2y, off);
        s3x += __shfl_xor(s3x, off); s3y += __shfl_xor(s3y, off);
    }
    if (node + lane < N_NODES) {                 // static accumulator select
        if      (lane == 0) t2[node]     = make_float2(s0x, s0y);
        else if (lane == 1) t2[node + 1] = make_float2(s1x, s1y);
        else if (lane == 2) t2[node + 2] = make_float2(s2x, s2y);
        else if (lane == 3) t2[node + 3] = make_float2(s3x, s3y);
    }
}

// Per bucket: local degree count -> dinv; scale t2 in place. 16 waves/block.
__global__ __launch_bounds__(1024) void k_dinv(const int* __restrict__ bbase,
                                               const int* __restrict__ binned,
                                               float* __restrict__ dinv,
                                               float2* __restrict__ t2) {
    __shared__ int cnt[256];
    if (threadIdx.x < 256) cnt[threadIdx.x] = 0;
    __syncthreads();
    int b = blockIdx.x;
    int s = bbase[b], e = bbase[b + 1];
    for (int i = s + threadIdx.x; i < e; i += 1024)
        atomicAdd(&cnt[binned[i] >> 20], 1);
    __syncthreads();
    if (threadIdx.x < 256) {
        int node = (b << 8) + threadIdx.x;
        if (node < N_NODES) {
            float di = rsqrtf((float)(cnt[threadIdx.x] + 1));  // +1 self loop
            dinv[node] = di;
            float2 v = t2[node];
            t2[node] = make_float2(v.x * di, v.y * di);
        }
    }
}

// Per bucket: accumulate pre-scaled t[src] in LDS, fused epilogue, dense out.
__global__ __launch_bounds__(1024) void k_acc(const int* __restrict__ bbase,
                                              const int* __restrict__ binned,
                                              const float2* __restrict__ t2,
                                              const float* __restrict__ dinv,
                                              const float* __restrict__ bconst,
                                              float2* __restrict__ out) {
    __shared__ float acc0[256];
    __shared__ float acc1[256];
    if (threadIdx.x < 256) {
        acc0[threadIdx.x] = 0.f;
        acc1[threadIdx.x] = 0.f;
    }
    __syncthreads();
    int b = blockIdx.x;
    int s = bbase[b], e = bbase[b + 1];
    for (int i = s + threadIdx.x; i < e; i += 1024) {
        int v = binned[i];
        float2 ts = t2[v & 0xFFFFF];    // L2-resident 800 KB table
        atomicAdd(&acc0[v >> 20], ts.x);
        atomicAdd(&acc1[v >> 20], ts.y);
    }
    __syncthreads();
    if (threadIdx.x < 256) {
        int node = (b << 8) + threadIdx.x;
        if (node < N_NODES) {
            float2 self = t2[node];     // already dinv-scaled
            float di = dinv[node];
            out[node] = make_float2(di * (acc0[threadIdx.x] + self.x) + bconst[0],
                                    di * (acc1[threadIdx.x] + self.y) + bconst[1]);
        }
    }
}

extern "C" void kernel_launch(void* const* d_in, const int* in_sizes, int n_in,
                              void* d_out, int out_size, void* d_ws, size_t ws_size,
                              hipStream_t stream) {
    const float* x  = (const float*)d_in[0];
    const int*   ei = (const int*)d_in[1];
    const float* W1 = (const float*)d_in[2];
    const float* b1 = (const float*)d_in[3];
    const float* W2 = (const float*)d_in[4];
    const float* b2 = (const float*)d_in[5];

    char* ws = (char*)d_ws;
    int*    hist   = (int*)   (ws + 0);
    int*    coltot = (int*)   (ws + 500480);
    int*    bbase  = (int*)   (ws + 502048);
    float*  Wc     = (float*) (ws + 503616);
    float*  bconst = (float*) (ws + 507712);
    float*  dinv   = (float*) (ws + 507728);
    float2* t2     = (float2*)(ws + 907728);
    int*    binned = (int*)   (ws + 1707728);

    k_count_wc<<<BIN_BLOCKS + 1, 1024, 0, stream>>>(ei + N_EDGES, hist,
                                                    W1, b1, W2, b2, Wc, bconst);
    k_colscan <<<NBUCK, 64, 0, stream>>>(hist, coltot);
    k_basescan<<<1, 512, 0, stream>>>(coltot, bbase);
    k_bin_xw  <<<BIN_BLOCKS + XW_BLOCKS, 1024, 0, stream>>>(ei, hist, coltot,
                                                            bbase, binned,
                                                            x, Wc, t2);
    k_dinv    <<<NBUCK, 1024, 0, stream>>>(bbase, binned, dinv, t2);
    k_acc     <<<NBUCK, 1024, 0, stream>>>(bbase, binned, t2, dinv, bconst,
                                           (float2*)d_out);
}